// Round 5
// baseline (519.178 us; speedup 1.0000x reference)
//
#include <hip/hip_runtime.h>
#include <hip/hip_bf16.h>

typedef unsigned short u16;
typedef unsigned int   u32;
typedef float  f32x4  __attribute__((ext_vector_type(4)));
typedef __bf16 bf16x8 __attribute__((ext_vector_type(8)));
typedef u16    u16x8  __attribute__((ext_vector_type(8)));
typedef u16    u16x4  __attribute__((ext_vector_type(4)));

__device__ __forceinline__ u16 f2bf(float f) {
  u32 x = __builtin_bit_cast(u32, f);
  x += 0x7fffu + ((x >> 16) & 1u);          // RNE
  return (u16)(x >> 16);
}
__device__ __forceinline__ float bf2f(u16 u) {
  return __builtin_bit_cast(float, (u32)u << 16);
}
__device__ __forceinline__ void gload_lds16(const u16* g, u16* l) {
  __builtin_amdgcn_global_load_lds(
      (const __attribute__((address_space(1))) void*)g,
      (__attribute__((address_space(3))) void*)l, 16, 0, 0);
}

// ---------------- convert x -> bf16 (each thread: 8 elems) ----------------
__global__ void k_conv_x(const float* __restrict__ x, u16* __restrict__ xb) {
  int g = blockIdx.x * 256 + threadIdx.x;          // 4,194,304 threads exact
  const float4* src = (const float4*)(x + (size_t)g * 8);
  float4 f0 = src[0], f1 = src[1];
  u16x8 o;
  o[0]=f2bf(f0.x); o[1]=f2bf(f0.y); o[2]=f2bf(f0.z); o[3]=f2bf(f0.w);
  o[4]=f2bf(f1.x); o[5]=f2bf(f1.y); o[6]=f2bf(f1.z); o[7]=f2bf(f1.w);
  *(u16x8*)(xb + (size_t)g * 8) = o;
}

// ------------- convert weights -> bf16, build concat bias -----------------
__global__ void k_conv_w(const float* __restrict__ Wu, const float* __restrict__ Wv,
                         const float* __restrict__ Wo, const float* __restrict__ bu,
                         const float* __restrict__ bv, u16* __restrict__ wuvb,
                         u16* __restrict__ wob, float* __restrict__ biasuv) {
  int g = blockIdx.x * 256 + threadIdx.x;          // 393,216 threads exact
  int e = g * 4;
  const float* src; u16* dst;
  if (e < 524288)        { src = Wu + e;             dst = wuvb + e; }
  else if (e < 1048576)  { src = Wv + (e - 524288);  dst = wuvb + e; }
  else                   { src = Wo + (e - 1048576); dst = wob + (e - 1048576); }
  float4 f = *(const float4*)src;
  u16x4 o; o[0]=f2bf(f.x); o[1]=f2bf(f.y); o[2]=f2bf(f.z); o[3]=f2bf(f.w);
  *(u16x4*)dst = o;
  if (g < 2048) biasuv[g] = (g < 1024) ? bu[g] : bv[g - 1024];
}

// ------------- T matrices: T[h] = (Wm U)(Wm V)^T, 64x64 per head ----------
__global__ void k_toep(const float* __restrict__ U1, const float* __restrict__ V1,
                       const float* __restrict__ U2, const float* __restrict__ V2,
                       u16* __restrict__ T1b, u16* __restrict__ T2b) {
  __shared__ float Us[512], Vs[512];
  int bid = blockIdx.x, t = threadIdx.x;
  int which = bid >> 6, rest = bid & 63, h = rest >> 3, seg = rest & 7;
  const float* U = which ? U2 : U1;
  const float* V = which ? V2 : V1;
  u16* T = which ? T2b : T1b;
  float scale = which ? 2.0f : 1.0f;
  for (int i = t; i < 512; i += 256) { Us[i] = U[h*512 + i]; Vs[i] = V[h*512 + i]; }
  __syncthreads();
  for (int q = 0; q < 2; ++q) {
    int e = seg * 512 + q * 256 + t;               // 0..4095 per head
    int i = e >> 6, j = e & 63;
    float pi = 1.0f / (float)(i + 1); float tvi = pi * 15.0f;
    int ii = min((int)floorf(tvi), 14); float fi = tvi - (float)ii;
    float pj = 1.0f / (float)(j + 1); float tvj = pj * 15.0f;
    int jj = min((int)floorf(tvj), 14); float fj = tvj - (float)jj;
    float s = 0.0f;
    #pragma unroll
    for (int r = 0; r < 32; ++r) {
      float a = (1.0f - fi) * Us[ii*32 + r] + fi * Us[(ii+1)*32 + r];
      float b = (1.0f - fj) * Vs[jj*32 + r] + fj * Vs[(jj+1)*32 + r];
      s += a * b;
    }
    T[h*4096 + i*64 + j] = f2bf(s * scale);
  }
}

// ============ persistent 256x256 bf16 B^T GEMM, phase-gated 8-phase ========
// C[m,n] = sum_k A[m,k]*B[n,k] (+bias[n]); EPI 0: silu->bf16, EPI 1: f32.
// Grid = 256 (1 block/CU). Block e: bn = e&(2^LGNBN-1) fixed, bm = (e>>LGNBN)
// + s*(256/NSEQ) for s = 0..NSEQ-1. K-tile index runs CONTINUOUSLY over
// s*NT+kt so the staging pipeline (2-tile lookahead, counted vmcnt) never
// drains at output-tile switches; per-seq epilogue runs with next-seq loads
// in flight. Staging/liveness schedule identical to r3 (race-free proof
// depends only on the continuous tile index).
template<int EPI, int K, int NSEQ, int LGNBN, int LDC>
__global__ __launch_bounds__(512, 2) void k_gemm256(
    const u16* __restrict__ A, const u16* __restrict__ B,
    const float* __restrict__ bias, void* __restrict__ C) {
  constexpr int NT = K >> 6;
  constexpr int LGNT = (NT == 8) ? 3 : 4;
  constexpr int TOT = NSEQ * NT;
  constexpr int SMSTEP = 256 / NSEQ;
  constexpr size_t SEQA = (size_t)SMSTEP * 256 * K;   // elems per seq A-step
  extern __shared__ uint4 smem4[];
  u16* lds = (u16*)smem4;
  const int t = threadIdx.x;
  const int l = t & 63, w = t >> 6;
  const int wmi = w >> 2, wni = w & 3;
  const int e = (blockIdx.x & 7) * 32 + (blockIdx.x >> 3);   // XCD swizzle
  const int bn = e & ((1 << LGNBN) - 1);
  const int bm0 = e >> LGNBN;
  const u16* Ab = A + (size_t)bm0 * 256 * K;
  const u16* Bb = B + (size_t)bn * 256 * K;

  f32x4 acc[8][4];                     // [h*4+f][nf]
  #pragma unroll
  for (int i = 0; i < 8; ++i)
    #pragma unroll
    for (int j = 0; j < 4; ++j) acc[i][j] = (f32x4){0.f, 0.f, 0.f, 0.f};

  float bcol[4];
  #pragma unroll
  for (int nf = 0; nf < 4; ++nf)
    bcol[nf] = bias[bn * 256 + (wni << 6) + nf * 16 + (l & 15)];

#define STAGE(TILE, HALF) do {                                               \
    int _t = (TILE);                                                         \
    int _seq = _t >> LGNT;                                                   \
    size_t _kt = (size_t)((_t & (NT - 1)) << 6);                             \
    const u16* _src = ((HALF) < 2) ? (Ab + (size_t)_seq * SEQA) : Bb;        \
    constexpr int _rowbase = ((HALF) & 1) << 7;                              \
    u16* _dst = lds + (_t & 1) * 32768 + (((HALF) >= 2) ? 16384 : 0)         \
                + _rowbase * 64;                                             \
    _Pragma("unroll")                                                        \
    for (int _j = 0; _j < 2; ++_j) {                                         \
      int _idx = _j * 512 + t;                                               \
      int _rr = _idx >> 3, _s8 = _idx & 7;                                   \
      int _R = _rowbase + _rr;                                               \
      int _col = (_s8 ^ (_R & 7)) << 3;                                      \
      gload_lds16(_src + (size_t)_R * K + _kt + _col, _dst + _idx * 8);      \
    }                                                                        \
  } while (0)

#define READ_A(hh, fp) do {                                                  \
    _Pragma("unroll")                                                        \
    for (int ks = 0; ks < 2; ++ks)                                           \
      _Pragma("unroll")                                                      \
      for (int i = 0; i < 2; ++i) {                                          \
        int R = ((hh) << 7) + (wmi << 6) + ((fp) * 2 + i) * 16 + (l & 15);   \
        int q8 = ks * 4 + (l >> 4);                                          \
        af[ks*2+i] = *(const bf16x8*)&As[R * 64 + ((q8 ^ (R & 7)) << 3)];    \
      }                                                                      \
  } while (0)

#define MFMA_PHASE(hh, fp) do {                                              \
    __builtin_amdgcn_s_setprio(1);                                           \
    _Pragma("unroll")                                                        \
    for (int ks = 0; ks < 2; ++ks)                                           \
      _Pragma("unroll")                                                      \
      for (int i = 0; i < 2; ++i)                                            \
        _Pragma("unroll")                                                    \
        for (int nf = 0; nf < 4; ++nf)                                       \
          acc[(hh)*4+(fp)*2+i][nf] = __builtin_amdgcn_mfma_f32_16x16x32_bf16(\
              af[ks*2+i], bfv[ks*4+nf], acc[(hh)*4+(fp)*2+i][nf], 0, 0, 0);  \
    __builtin_amdgcn_s_setprio(0);                                           \
  } while (0)

  // prologue: tile0 {A0,A1,B0,B1} then tile1 {B0,B1,A0}; drain tile0 only.
  STAGE(0, 0); STAGE(0, 1); STAGE(0, 2); STAGE(0, 3);
  STAGE(1, 2); STAGE(1, 3); STAGE(1, 0);
  asm volatile("s_waitcnt vmcnt(6)");
  __builtin_amdgcn_s_barrier();

  for (int tile = 0; tile < TOT; ++tile) {
    const u16* As = lds + (tile & 1) * 32768;
    const u16* Bs = As + 16384;
    bf16x8 bfv[8];                       // [ks*4+nf], held all 4 phases
    bf16x8 af[4];                        // [ks*2+i], per phase

    // ---------- phase 0: B(8 reads) + A h0 f0-1; issue (t+1).A1 ----------
    #pragma unroll
    for (int ks = 0; ks < 2; ++ks)
      #pragma unroll
      for (int nf = 0; nf < 4; ++nf) {
        int R = (wni << 6) + nf * 16 + (l & 15);
        int q8 = ks * 4 + (l >> 4);
        bfv[ks*4+nf] = *(const bf16x8*)&Bs[R * 64 + ((q8 ^ (R & 7)) << 3)];
      }
    READ_A(0, 0);
    if (tile + 1 < TOT) STAGE(tile + 1, 1);
    __builtin_amdgcn_s_barrier();
    asm volatile("s_waitcnt lgkmcnt(0)");
    MFMA_PHASE(0, 0);
    __builtin_amdgcn_s_barrier();

    // ---------- phase 1: A h0 f2-3; issue (t+2).B0,B1; vmcnt gate ----------
    READ_A(0, 1);
    if (tile + 2 < TOT) { STAGE(tile + 2, 2); STAGE(tile + 2, 3); }
    __builtin_amdgcn_s_barrier();
    asm volatile("s_waitcnt lgkmcnt(0)");
    MFMA_PHASE(0, 1);
    if (tile < TOT - 2)       asm volatile("s_waitcnt vmcnt(12)");
    else if (tile == TOT - 2) asm volatile("s_waitcnt vmcnt(8)");
    else                      asm volatile("s_waitcnt vmcnt(0)");
    __builtin_amdgcn_s_barrier();

    // ---------- phase 2: A h1 f0-1; issue (t+2).A0 ----------
    READ_A(1, 0);
    if (tile + 2 < TOT) STAGE(tile + 2, 0);
    __builtin_amdgcn_s_barrier();
    asm volatile("s_waitcnt lgkmcnt(0)");
    MFMA_PHASE(1, 0);
    __builtin_amdgcn_s_barrier();

    // ---------- phase 3: A h1 f2-3; vmcnt gate for next tile ----------
    READ_A(1, 1);
    __builtin_amdgcn_s_barrier();
    asm volatile("s_waitcnt lgkmcnt(0)");
    MFMA_PHASE(1, 1);
    if (tile < TOT - 2)       asm volatile("s_waitcnt vmcnt(8)");
    else if (tile == TOT - 2) asm volatile("s_waitcnt vmcnt(2)");
    __builtin_amdgcn_s_barrier();

    // ---------- per-seq epilogue (loads for next seq stay in flight) ------
    if ((tile & (NT - 1)) == NT - 1) {
      int s = tile >> LGNT;
      int bmbase = (bm0 + s * SMSTEP) * 256;
      #pragma unroll
      for (int hf = 0; hf < 8; ++hf) {
        int gm0 = bmbase + (hf >> 2) * 128 + wmi * 64 + (hf & 3) * 16 + (l >> 4) * 4;
        #pragma unroll
        for (int nf = 0; nf < 4; ++nf) {
          int gn = bn * 256 + (wni << 6) + nf * 16 + (l & 15);
          #pragma unroll
          for (int r = 0; r < 4; ++r) {
            float z = acc[hf][nf][r] + bcol[nf];
            size_t off = (size_t)(gm0 + r) * LDC + gn;
            if (EPI == 0) {
              z = z / (1.0f + __expf(-z));           // silu
              ((u16*)C)[off] = f2bf(z);
            } else {
              ((float*)C)[off] = z;
            }
          }
        }
      }
      #pragma unroll
      for (int i = 0; i < 8; ++i)
        #pragma unroll
        for (int j = 0; j < 4; ++j) acc[i][j] = (f32x4){0.f, 0.f, 0.f, 0.f};
    }
  }
#undef STAGE
#undef READ_A
#undef MFMA_PHASE
}

// ------------- mixing pass: per (b,outer,h): Out = T @ In (64x64 @ 64x128) -
template<int PASS>
__global__ __launch_bounds__(256) void k_mix(const u16* __restrict__ uv,
                                             u16* __restrict__ y,
                                             const u16* __restrict__ Tmat) {
  __shared__ alignas(16) u16 Ts[64 * 72];     // T padded rows (72 elems)
  __shared__ alignas(16) u32 VT[128 * 36];    // transposed input, swizzled
  int bid = blockIdx.x, t = threadIdx.x;
  int h = bid & 7, outer = (bid >> 3) & 63, b = bid >> 9;
  int l = t & 63, w = t >> 6;

  { // stage T[h] (64x64 bf16) into padded LDS
    const u16* Tg = Tmat + h * 4096;
    int rr = t >> 2, cc = (t & 3) * 16;
    const uint4* src = (const uint4*)(Tg + rr * 64 + cc);
    uint4 v0 = src[0], v1 = src[1];
    *(uint4*)&Ts[rr * 72 + cc] = v0;
    *(uint4*)&Ts[rr * 72 + cc + 8] = v1;
  }

  size_t inbase; size_t instride;
  if (PASS == 0) { inbase = ((size_t)(b*64 + outer) * 64) * 2048 + 1024 + h*128; instride = 2048; }
  else           { inbase = ((size_t)b * 4096 + outer) * 1024 + h*128;            instride = 65536; }
  const u16* inp = (PASS == 0) ? uv : (const u16*)y;

  #pragma unroll
  for (int a2 = 0; a2 < 2; ++a2) {
    int jp = (t >> 4) + a2 * 16;                 // row-pair 0..31 (rows 2jp,2jp+1)
    int dc = t & 15;                             // d-chunk of 8
    const u16* r0 = inp + inbase + (size_t)(2*jp) * instride + dc * 8;
    const u16* r1 = r0 + instride;
    uint4 av = *(const uint4*)r0;
    uint4 bv = *(const uint4*)r1;
    u32 a4[4] = {av.x, av.y, av.z, av.w};
    u32 b4[4] = {bv.x, bv.y, bv.z, bv.w};
    #pragma unroll
    for (int ww = 0; ww < 4; ++ww) {
      u32 lo = (a4[ww] & 0xffffu) | (b4[ww] << 16);        // d even
      u32 hi = (a4[ww] >> 16) | (b4[ww] & 0xffff0000u);    // d odd
      int d0 = dc * 8 + 2 * ww, d1 = d0 + 1;
      VT[d0 * 36 + (jp ^ ((((u32)d0 >> 3) & 7) << 2))] = lo;
      VT[d1 * 36 + (jp ^ ((((u32)d1 >> 3) & 7) << 2))] = hi;
    }
  }
  __syncthreads();

  f32x4 acc[8];
  #pragma unroll
  for (int nf = 0; nf < 8; ++nf) acc[nf] = (f32x4){0.f, 0.f, 0.f, 0.f};
  #pragma unroll
  for (int ks = 0; ks < 2; ++ks) {
    bf16x8 af = *(const bf16x8*)&Ts[(w*16 + (l & 15)) * 72 + ks*32 + (l >> 4)*8];
    #pragma unroll
    for (int nf = 0; nf < 8; ++nf) {
      int d  = nf * 16 + (l & 15);
      int kd = ks * 16 + (l >> 4) * 4;
      u32 dw = (u32)d * 36 + ((u32)kd ^ ((((u32)d >> 3) & 7) << 2));
      bf16x8 bfv = *(const bf16x8*)&VT[dw];
      acc[nf] = __builtin_amdgcn_mfma_f32_16x16x32_bf16(af, bfv, acc[nf], 0, 0, 0);
    }
  }

  size_t obase, ostride, ubase = 0;
  if (PASS == 0) { obase = ((size_t)(b*64 + outer) * 64) * 1024 + h*128; ostride = 1024; }
  else {
    obase = ((size_t)b * 4096 + outer) * 1024 + h*128; ostride = 65536;
    ubase = ((size_t)b * 4096 + outer) * 2048 + h*128;
  }
  #pragma unroll
  for (int nf = 0; nf < 8; ++nf) {
    int d = nf * 16 + (l & 15);
    #pragma unroll
    for (int r = 0; r < 4; ++r) {
      int m = w * 16 + (l >> 4) * 4 + r;
      float val = acc[nf][r];
      if (PASS == 1) val *= bf2f(uv[ubase + (size_t)m * 131072 + d]);
      y[obase + (size_t)m * ostride + d] = f2bf(val);
    }
  }
}

// ---------------------------------------------------------------------------
extern "C" void kernel_launch(void* const* d_in, const int* in_sizes, int n_in,
                              void* d_out, int out_size, void* d_ws, size_t ws_size,
                              hipStream_t stream) {
  const float* x  = (const float*)d_in[0];
  const float* Wu = (const float*)d_in[1];
  const float* bu = (const float*)d_in[2];
  const float* Wv = (const float*)d_in[3];
  const float* bv = (const float*)d_in[4];
  const float* Wo = (const float*)d_in[5];
  const float* bo = (const float*)d_in[6];
  const float* U1 = (const float*)d_in[7];
  const float* V1 = (const float*)d_in[8];
  const float* U2 = (const float*)d_in[9];
  const float* V2 = (const float*)d_in[10];
  float* out = (float*)d_out;

  char* p = (char*)d_ws;
  u16*  xb     = (u16*)(p + 0);              //  67,108,864 B
  u16*  wuvb   = (u16*)(p + 67108864);       //   2,097,152 B
  u16*  wob    = (u16*)(p + 69206016);       //   1,048,576 B
  u16*  T1b    = (u16*)(p + 70254592);       //      65,536 B
  u16*  T2b    = (u16*)(p + 70320128);       //      65,536 B
  float* biasuv= (float*)(p + 70385664);     //       8,192 B
  u16*  uv     = (u16*)(p + 70393856);       // 268,435,456 B  (u|v, ld 2048)
  u16*  y      = (u16*)(p + 338829312);      // 134,217,728 B  -> end 473,047,040
  if (ws_size < 473047040ULL) return;        // insufficient scratch: visible fail

  // allow 128 KiB dynamic LDS (ignore failures; ROCm typically allows directly)
  (void)hipFuncSetAttribute((const void*)&k_gemm256<0, 512, 8, 3, 2048>,
      hipFuncAttributeMaxDynamicSharedMemorySize, 131072);
  (void)hipFuncSetAttribute((const void*)&k_gemm256<1, 1024, 2, 1, 512>,
      hipFuncAttributeMaxDynamicSharedMemorySize, 131072);

  k_conv_x<<<16384, 256, 0, stream>>>(x, xb);
  k_conv_w<<<1536, 256, 0, stream>>>(Wu, Wv, Wo, bu, bv, wuvb, wob, biasuv);
  k_toep<<<128, 256, 0, stream>>>(U1, V1, U2, V2, T1b, T2b);
  // uv = [silu(x Wu^T + bu) | silu(x Wv^T + bv)]  (M=65536, N=2048, K=512)
  k_gemm256<0, 512, 8, 3, 2048><<<256, 512, 131072, stream>>>(xb, wuvb, biasuv, (void*)uv);
  // y = T1-mix along W of v
  k_mix<0><<<8192, 256, 0, stream>>>(uv, y, T1b);
  // y = u * (2*T2)-mix along H of y   (in-place, gated)
  k_mix<1><<<8192, 256, 0, stream>>>(uv, y, T2b);
  // out = y Wo^T + bo  (M=65536, N=512, K=1024)
  k_gemm256<1, 1024, 2, 1, 512><<<256, 512, 131072, stream>>>(y, wob, bo, (void*)out);
}

// Round 6
// 519.138 us; speedup vs baseline: 1.0001x; 1.0001x over previous
//
#include <hip/hip_runtime.h>
#include <hip/hip_bf16.h>

typedef unsigned short u16;
typedef unsigned int   u32;
typedef float  f32x4  __attribute__((ext_vector_type(4)));
typedef __bf16 bf16x8 __attribute__((ext_vector_type(8)));
typedef u16    u16x8  __attribute__((ext_vector_type(8)));
typedef u16    u16x4  __attribute__((ext_vector_type(4)));

__device__ __forceinline__ u16 f2bf(float f) {
  u32 x = __builtin_bit_cast(u32, f);
  x += 0x7fffu + ((x >> 16) & 1u);          // RNE
  return (u16)(x >> 16);
}
__device__ __forceinline__ float bf2f(u16 u) {
  return __builtin_bit_cast(float, (u32)u << 16);
}
__device__ __forceinline__ void gload_lds16(const u16* g, u16* l) {
  __builtin_amdgcn_global_load_lds(
      (const __attribute__((address_space(1))) void*)g,
      (__attribute__((address_space(3))) void*)l, 16, 0, 0);
}

// ---------------- convert x -> bf16 (each thread: 8 elems) ----------------
__global__ void k_conv_x(const float* __restrict__ x, u16* __restrict__ xb) {
  int g = blockIdx.x * 256 + threadIdx.x;          // 4,194,304 threads exact
  const float4* src = (const float4*)(x + (size_t)g * 8);
  float4 f0 = src[0], f1 = src[1];
  u16x8 o;
  o[0]=f2bf(f0.x); o[1]=f2bf(f0.y); o[2]=f2bf(f0.z); o[3]=f2bf(f0.w);
  o[4]=f2bf(f1.x); o[5]=f2bf(f1.y); o[6]=f2bf(f1.z); o[7]=f2bf(f1.w);
  *(u16x8*)(xb + (size_t)g * 8) = o;
}

// ------------- convert weights -> bf16, build concat bias -----------------
__global__ void k_conv_w(const float* __restrict__ Wu, const float* __restrict__ Wv,
                         const float* __restrict__ Wo, const float* __restrict__ bu,
                         const float* __restrict__ bv, u16* __restrict__ wuvb,
                         u16* __restrict__ wob, float* __restrict__ biasuv) {
  int g = blockIdx.x * 256 + threadIdx.x;          // 393,216 threads exact
  int e = g * 4;
  const float* src; u16* dst;
  if (e < 524288)        { src = Wu + e;             dst = wuvb + e; }
  else if (e < 1048576)  { src = Wv + (e - 524288);  dst = wuvb + e; }
  else                   { src = Wo + (e - 1048576); dst = wob + (e - 1048576); }
  float4 f = *(const float4*)src;
  u16x4 o; o[0]=f2bf(f.x); o[1]=f2bf(f.y); o[2]=f2bf(f.z); o[3]=f2bf(f.w);
  *(u16x4*)dst = o;
  if (g < 2048) biasuv[g] = (g < 1024) ? bu[g] : bv[g - 1024];
}

// ------------- T matrices: T[h] = (Wm U)(Wm V)^T, 64x64 per head ----------
__global__ void k_toep(const float* __restrict__ U1, const float* __restrict__ V1,
                       const float* __restrict__ U2, const float* __restrict__ V2,
                       u16* __restrict__ T1b, u16* __restrict__ T2b) {
  __shared__ float Us[512], Vs[512];
  int bid = blockIdx.x, t = threadIdx.x;
  int which = bid >> 6, rest = bid & 63, h = rest >> 3, seg = rest & 7;
  const float* U = which ? U2 : U1;
  const float* V = which ? V2 : V1;
  u16* T = which ? T2b : T1b;
  float scale = which ? 2.0f : 1.0f;
  for (int i = t; i < 512; i += 256) { Us[i] = U[h*512 + i]; Vs[i] = V[h*512 + i]; }
  __syncthreads();
  for (int q = 0; q < 2; ++q) {
    int e = seg * 512 + q * 256 + t;               // 0..4095 per head
    int i = e >> 6, j = e & 63;
    float pi = 1.0f / (float)(i + 1); float tvi = pi * 15.0f;
    int ii = min((int)floorf(tvi), 14); float fi = tvi - (float)ii;
    float pj = 1.0f / (float)(j + 1); float tvj = pj * 15.0f;
    int jj = min((int)floorf(tvj), 14); float fj = tvj - (float)jj;
    float s = 0.0f;
    #pragma unroll
    for (int r = 0; r < 32; ++r) {
      float a = (1.0f - fi) * Us[ii*32 + r] + fi * Us[(ii+1)*32 + r];
      float b = (1.0f - fj) * Vs[jj*32 + r] + fj * Vs[(jj+1)*32 + r];
      s += a * b;
    }
    T[h*4096 + i*64 + j] = f2bf(s * scale);
  }
}

// ============ persistent 256x256 bf16 B^T GEMM, phase-gated 8-phase ========
// C[m,n] = sum_k A[m,k]*B[n,k] (+bias[n]); EPI 0: silu->bf16, EPI 1: f32.
// Grid = 256 (1 block/CU). Block e: bn = e&(2^LGNBN-1) fixed, bm = (e>>LGNBN)
// + s*(256/NSEQ) for s = 0..NSEQ-1. K-tile index runs CONTINUOUSLY over
// s*NT+kt so the staging pipeline (2-tile lookahead, counted vmcnt) never
// drains at output-tile switches; per-seq epilogue runs with next-seq loads
// in flight. Staging/liveness schedule identical to r3 (race-free proof
// depends only on the continuous tile index).
template<int EPI, int K, int NSEQ, int LGNBN, int LDC>
__global__ __launch_bounds__(512, 2) void k_gemm256(
    const u16* __restrict__ A, const u16* __restrict__ B,
    const float* __restrict__ bias, void* __restrict__ C) {
  constexpr int NT = K >> 6;
  constexpr int LGNT = (NT == 8) ? 3 : 4;
  constexpr int TOT = NSEQ * NT;
  constexpr int SMSTEP = 256 / NSEQ;
  constexpr size_t SEQA = (size_t)SMSTEP * 256 * K;   // elems per seq A-step
  extern __shared__ uint4 smem4[];
  u16* lds = (u16*)smem4;
  const int t = threadIdx.x;
  const int l = t & 63, w = t >> 6;
  const int wmi = w >> 2, wni = w & 3;
  const int e = (blockIdx.x & 7) * 32 + (blockIdx.x >> 3);   // XCD swizzle
  const int bn = e & ((1 << LGNBN) - 1);
  const int bm0 = e >> LGNBN;
  const u16* Ab = A + (size_t)bm0 * 256 * K;
  const u16* Bb = B + (size_t)bn * 256 * K;

  f32x4 acc[8][4];                     // [h*4+f][nf]
  #pragma unroll
  for (int i = 0; i < 8; ++i)
    #pragma unroll
    for (int j = 0; j < 4; ++j) acc[i][j] = (f32x4){0.f, 0.f, 0.f, 0.f};

  float bcol[4];
  #pragma unroll
  for (int nf = 0; nf < 4; ++nf)
    bcol[nf] = bias[bn * 256 + (wni << 6) + nf * 16 + (l & 15)];

#define STAGE(TILE, HALF) do {                                               \
    int _t = (TILE);                                                         \
    int _seq = _t >> LGNT;                                                   \
    size_t _kt = (size_t)((_t & (NT - 1)) << 6);                             \
    const u16* _src = ((HALF) < 2) ? (Ab + (size_t)_seq * SEQA) : Bb;        \
    constexpr int _rowbase = ((HALF) & 1) << 7;                              \
    u16* _dst = lds + (_t & 1) * 32768 + (((HALF) >= 2) ? 16384 : 0)         \
                + _rowbase * 64;                                             \
    _Pragma("unroll")                                                        \
    for (int _j = 0; _j < 2; ++_j) {                                         \
      int _idx = _j * 512 + t;                                               \
      int _rr = _idx >> 3, _s8 = _idx & 7;                                   \
      int _R = _rowbase + _rr;                                               \
      int _col = (_s8 ^ (_R & 7)) << 3;                                      \
      gload_lds16(_src + (size_t)_R * K + _kt + _col, _dst + _idx * 8);      \
    }                                                                        \
  } while (0)

#define READ_A(hh, fp) do {                                                  \
    _Pragma("unroll")                                                        \
    for (int ks = 0; ks < 2; ++ks)                                           \
      _Pragma("unroll")                                                      \
      for (int i = 0; i < 2; ++i) {                                          \
        int R = ((hh) << 7) + (wmi << 6) + ((fp) * 2 + i) * 16 + (l & 15);   \
        int q8 = ks * 4 + (l >> 4);                                          \
        af[ks*2+i] = *(const bf16x8*)&As[R * 64 + ((q8 ^ (R & 7)) << 3)];    \
      }                                                                      \
  } while (0)

#define MFMA_PHASE(hh, fp) do {                                              \
    __builtin_amdgcn_s_setprio(1);                                           \
    _Pragma("unroll")                                                        \
    for (int ks = 0; ks < 2; ++ks)                                           \
      _Pragma("unroll")                                                      \
      for (int i = 0; i < 2; ++i)                                            \
        _Pragma("unroll")                                                    \
        for (int nf = 0; nf < 4; ++nf)                                       \
          acc[(hh)*4+(fp)*2+i][nf] = __builtin_amdgcn_mfma_f32_16x16x32_bf16(\
              af[ks*2+i], bfv[ks*4+nf], acc[(hh)*4+(fp)*2+i][nf], 0, 0, 0);  \
    __builtin_amdgcn_s_setprio(0);                                           \
  } while (0)

  // prologue: tile0 {A0,A1,B0,B1} then tile1 {B0,B1,A0}; drain tile0 only.
  STAGE(0, 0); STAGE(0, 1); STAGE(0, 2); STAGE(0, 3);
  STAGE(1, 2); STAGE(1, 3); STAGE(1, 0);
  asm volatile("s_waitcnt vmcnt(6)");
  __builtin_amdgcn_s_barrier();

  for (int tile = 0; tile < TOT; ++tile) {
    const u16* As = lds + (tile & 1) * 32768;
    const u16* Bs = As + 16384;
    bf16x8 bfv[8];                       // [ks*4+nf], held all 4 phases
    bf16x8 af[4];                        // [ks*2+i], per phase

    // ---------- phase 0: B(8 reads) + A h0 f0-1; issue (t+1).A1 ----------
    #pragma unroll
    for (int ks = 0; ks < 2; ++ks)
      #pragma unroll
      for (int nf = 0; nf < 4; ++nf) {
        int R = (wni << 6) + nf * 16 + (l & 15);
        int q8 = ks * 4 + (l >> 4);
        bfv[ks*4+nf] = *(const bf16x8*)&Bs[R * 64 + ((q8 ^ (R & 7)) << 3)];
      }
    READ_A(0, 0);
    if (tile + 1 < TOT) STAGE(tile + 1, 1);
    __builtin_amdgcn_s_barrier();
    asm volatile("s_waitcnt lgkmcnt(0)");
    MFMA_PHASE(0, 0);
    __builtin_amdgcn_s_barrier();

    // ---------- phase 1: A h0 f2-3; issue (t+2).B0,B1; vmcnt gate ----------
    READ_A(0, 1);
    if (tile + 2 < TOT) { STAGE(tile + 2, 2); STAGE(tile + 2, 3); }
    __builtin_amdgcn_s_barrier();
    asm volatile("s_waitcnt lgkmcnt(0)");
    MFMA_PHASE(0, 1);
    if (tile < TOT - 2)       asm volatile("s_waitcnt vmcnt(12)");
    else if (tile == TOT - 2) asm volatile("s_waitcnt vmcnt(8)");
    else                      asm volatile("s_waitcnt vmcnt(0)");
    __builtin_amdgcn_s_barrier();

    // ---------- phase 2: A h1 f0-1; issue (t+2).A0 ----------
    READ_A(1, 0);
    if (tile + 2 < TOT) STAGE(tile + 2, 0);
    __builtin_amdgcn_s_barrier();
    asm volatile("s_waitcnt lgkmcnt(0)");
    MFMA_PHASE(1, 0);
    __builtin_amdgcn_s_barrier();

    // ---------- phase 3: A h1 f2-3; vmcnt gate for next tile ----------
    READ_A(1, 1);
    __builtin_amdgcn_s_barrier();
    asm volatile("s_waitcnt lgkmcnt(0)");
    MFMA_PHASE(1, 1);
    if (tile < TOT - 2)       asm volatile("s_waitcnt vmcnt(8)");
    else if (tile == TOT - 2) asm volatile("s_waitcnt vmcnt(2)");
    __builtin_amdgcn_s_barrier();

    // ---------- per-seq epilogue (loads for next seq stay in flight) ------
    if ((tile & (NT - 1)) == NT - 1) {
      int s = tile >> LGNT;
      int bmbase = (bm0 + s * SMSTEP) * 256;
      #pragma unroll
      for (int hf = 0; hf < 8; ++hf) {
        int gm0 = bmbase + (hf >> 2) * 128 + wmi * 64 + (hf & 3) * 16 + (l >> 4) * 4;
        #pragma unroll
        for (int nf = 0; nf < 4; ++nf) {
          int gn = bn * 256 + (wni << 6) + nf * 16 + (l & 15);
          #pragma unroll
          for (int r = 0; r < 4; ++r) {
            float z = acc[hf][nf][r] + bcol[nf];
            size_t off = (size_t)(gm0 + r) * LDC + gn;
            if (EPI == 0) {
              z = z / (1.0f + __expf(-z));           // silu
              ((u16*)C)[off] = f2bf(z);
            } else {
              ((float*)C)[off] = z;
            }
          }
        }
      }
      #pragma unroll
      for (int i = 0; i < 8; ++i)
        #pragma unroll
        for (int j = 0; j < 4; ++j) acc[i][j] = (f32x4){0.f, 0.f, 0.f, 0.f};
    }
  }
#undef STAGE
#undef READ_A
#undef MFMA_PHASE
}

// ------------- mixing pass: per (b,outer,h): Out = T @ In (64x64 @ 64x128) -
template<int PASS>
__global__ __launch_bounds__(256) void k_mix(const u16* __restrict__ uv,
                                             u16* __restrict__ y,
                                             const u16* __restrict__ Tmat) {
  __shared__ alignas(16) u16 Ts[64 * 72];     // T padded rows (72 elems)
  __shared__ alignas(16) u32 VT[128 * 36];    // transposed input, swizzled
  int bid = blockIdx.x, t = threadIdx.x;
  int h = bid & 7, outer = (bid >> 3) & 63, b = bid >> 9;
  int l = t & 63, w = t >> 6;

  { // stage T[h] (64x64 bf16) into padded LDS
    const u16* Tg = Tmat + h * 4096;
    int rr = t >> 2, cc = (t & 3) * 16;
    const uint4* src = (const uint4*)(Tg + rr * 64 + cc);
    uint4 v0 = src[0], v1 = src[1];
    *(uint4*)&Ts[rr * 72 + cc] = v0;
    *(uint4*)&Ts[rr * 72 + cc + 8] = v1;
  }

  size_t inbase; size_t instride;
  if (PASS == 0) { inbase = ((size_t)(b*64 + outer) * 64) * 2048 + 1024 + h*128; instride = 2048; }
  else           { inbase = ((size_t)b * 4096 + outer) * 1024 + h*128;            instride = 65536; }
  const u16* inp = (PASS == 0) ? uv : (const u16*)y;

  #pragma unroll
  for (int a2 = 0; a2 < 2; ++a2) {
    int jp = (t >> 4) + a2 * 16;                 // row-pair 0..31 (rows 2jp,2jp+1)
    int dc = t & 15;                             // d-chunk of 8
    const u16* r0 = inp + inbase + (size_t)(2*jp) * instride + dc * 8;
    const u16* r1 = r0 + instride;
    uint4 av = *(const uint4*)r0;
    uint4 bv = *(const uint4*)r1;
    u32 a4[4] = {av.x, av.y, av.z, av.w};
    u32 b4[4] = {bv.x, bv.y, bv.z, bv.w};
    #pragma unroll
    for (int ww = 0; ww < 4; ++ww) {
      u32 lo = (a4[ww] & 0xffffu) | (b4[ww] << 16);        // d even
      u32 hi = (a4[ww] >> 16) | (b4[ww] & 0xffff0000u);    // d odd
      int d0 = dc * 8 + 2 * ww, d1 = d0 + 1;
      VT[d0 * 36 + (jp ^ ((((u32)d0 >> 3) & 7) << 2))] = lo;
      VT[d1 * 36 + (jp ^ ((((u32)d1 >> 3) & 7) << 2))] = hi;
    }
  }
  __syncthreads();

  f32x4 acc[8];
  #pragma unroll
  for (int nf = 0; nf < 8; ++nf) acc[nf] = (f32x4){0.f, 0.f, 0.f, 0.f};
  #pragma unroll
  for (int ks = 0; ks < 2; ++ks) {
    bf16x8 af = *(const bf16x8*)&Ts[(w*16 + (l & 15)) * 72 + ks*32 + (l >> 4)*8];
    #pragma unroll
    for (int nf = 0; nf < 8; ++nf) {
      int d  = nf * 16 + (l & 15);
      int kd = ks * 16 + (l >> 4) * 4;
      u32 dw = (u32)d * 36 + ((u32)kd ^ ((((u32)d >> 3) & 7) << 2));
      bf16x8 bfv = *(const bf16x8*)&VT[dw];
      acc[nf] = __builtin_amdgcn_mfma_f32_16x16x32_bf16(af, bfv, acc[nf], 0, 0, 0);
    }
  }

  size_t obase, ostride, ubase = 0;
  if (PASS == 0) { obase = ((size_t)(b*64 + outer) * 64) * 1024 + h*128; ostride = 1024; }
  else {
    obase = ((size_t)b * 4096 + outer) * 1024 + h*128; ostride = 65536;
    ubase = ((size_t)b * 4096 + outer) * 2048 + h*128;
  }
  #pragma unroll
  for (int nf = 0; nf < 8; ++nf) {
    int d = nf * 16 + (l & 15);
    #pragma unroll
    for (int r = 0; r < 4; ++r) {
      int m = w * 16 + (l >> 4) * 4 + r;
      float val = acc[nf][r];
      if (PASS == 1) val *= bf2f(uv[ubase + (size_t)m * 131072 + d]);
      y[obase + (size_t)m * ostride + d] = f2bf(val);
    }
  }
}

// ---------------------------------------------------------------------------
extern "C" void kernel_launch(void* const* d_in, const int* in_sizes, int n_in,
                              void* d_out, int out_size, void* d_ws, size_t ws_size,
                              hipStream_t stream) {
  const float* x  = (const float*)d_in[0];
  const float* Wu = (const float*)d_in[1];
  const float* bu = (const float*)d_in[2];
  const float* Wv = (const float*)d_in[3];
  const float* bv = (const float*)d_in[4];
  const float* Wo = (const float*)d_in[5];
  const float* bo = (const float*)d_in[6];
  const float* U1 = (const float*)d_in[7];
  const float* V1 = (const float*)d_in[8];
  const float* U2 = (const float*)d_in[9];
  const float* V2 = (const float*)d_in[10];
  float* out = (float*)d_out;

  char* p = (char*)d_ws;
  u16*  xb     = (u16*)(p + 0);              //  67,108,864 B
  u16*  wuvb   = (u16*)(p + 67108864);       //   2,097,152 B
  u16*  wob    = (u16*)(p + 69206016);       //   1,048,576 B
  u16*  T1b    = (u16*)(p + 70254592);       //      65,536 B
  u16*  T2b    = (u16*)(p + 70320128);       //      65,536 B
  float* biasuv= (float*)(p + 70385664);     //       8,192 B
  u16*  uv     = (u16*)(p + 70393856);       // 268,435,456 B  (u|v, ld 2048)
  u16*  y      = (u16*)(p + 338829312);      // 134,217,728 B  -> end 473,047,040
  if (ws_size < 473047040ULL) return;        // insufficient scratch: visible fail

  // allow 128 KiB dynamic LDS (ignore failures; ROCm typically allows directly)
  (void)hipFuncSetAttribute((const void*)&k_gemm256<0, 512, 8, 3, 2048>,
      hipFuncAttributeMaxDynamicSharedMemorySize, 131072);
  (void)hipFuncSetAttribute((const void*)&k_gemm256<1, 1024, 2, 1, 512>,
      hipFuncAttributeMaxDynamicSharedMemorySize, 131072);

  k_conv_x<<<16384, 256, 0, stream>>>(x, xb);
  k_conv_w<<<1536, 256, 0, stream>>>(Wu, Wv, Wo, bu, bv, wuvb, wob, biasuv);
  k_toep<<<128, 256, 0, stream>>>(U1, V1, U2, V2, T1b, T2b);
  // uv = [silu(x Wu^T + bu) | silu(x Wv^T + bv)]  (M=65536, N=2048, K=512)
  k_gemm256<0, 512, 8, 3, 2048><<<256, 512, 131072, stream>>>(xb, wuvb, biasuv, (void*)uv);
  // y = T1-mix along W of v
  k_mix<0><<<8192, 256, 0, stream>>>(uv, y, T1b);
  // y = u * (2*T2)-mix along H of y   (in-place, gated)
  k_mix<1><<<8192, 256, 0, stream>>>(uv, y, T2b);
  // out = y Wo^T + bo  (M=65536, N=512, K=1024)
  k_gemm256<1, 1024, 2, 1, 512><<<256, 512, 131072, stream>>>(y, wob, bo, (void*)out);
}

// Round 7
// 518.331 us; speedup vs baseline: 1.0016x; 1.0016x over previous
//
#include <hip/hip_runtime.h>
#include <hip/hip_bf16.h>

typedef unsigned short u16;
typedef unsigned int   u32;
typedef float  f32x4  __attribute__((ext_vector_type(4)));
typedef __bf16 bf16x8 __attribute__((ext_vector_type(8)));
typedef u16    u16x8  __attribute__((ext_vector_type(8)));
typedef u16    u16x4  __attribute__((ext_vector_type(4)));

__device__ __forceinline__ u16 f2bf(float f) {
  u32 x = __builtin_bit_cast(u32, f);
  x += 0x7fffu + ((x >> 16) & 1u);          // RNE
  return (u16)(x >> 16);
}
__device__ __forceinline__ float bf2f(u16 u) {
  return __builtin_bit_cast(float, (u32)u << 16);
}
__device__ __forceinline__ void gload_lds16(const u16* g, u16* l) {
  __builtin_amdgcn_global_load_lds(
      (const __attribute__((address_space(1))) void*)g,
      (__attribute__((address_space(3))) void*)l, 16, 0, 0);
}

// ---------------- convert x -> bf16 (each thread: 8 elems) ----------------
__global__ void k_conv_x(const float* __restrict__ x, u16* __restrict__ xb) {
  int g = blockIdx.x * 256 + threadIdx.x;          // 4,194,304 threads exact
  const float4* src = (const float4*)(x + (size_t)g * 8);
  float4 f0 = src[0], f1 = src[1];
  u16x8 o;
  o[0]=f2bf(f0.x); o[1]=f2bf(f0.y); o[2]=f2bf(f0.z); o[3]=f2bf(f0.w);
  o[4]=f2bf(f1.x); o[5]=f2bf(f1.y); o[6]=f2bf(f1.z); o[7]=f2bf(f1.w);
  *(u16x8*)(xb + (size_t)g * 8) = o;
}

// ------------- convert weights -> bf16, build concat bias -----------------
__global__ void k_conv_w(const float* __restrict__ Wu, const float* __restrict__ Wv,
                         const float* __restrict__ Wo, const float* __restrict__ bu,
                         const float* __restrict__ bv, u16* __restrict__ wuvb,
                         u16* __restrict__ wob, float* __restrict__ biasuv) {
  int g = blockIdx.x * 256 + threadIdx.x;          // 393,216 threads exact
  int e = g * 4;
  const float* src; u16* dst;
  if (e < 524288)        { src = Wu + e;             dst = wuvb + e; }
  else if (e < 1048576)  { src = Wv + (e - 524288);  dst = wuvb + e; }
  else                   { src = Wo + (e - 1048576); dst = wob + (e - 1048576); }
  float4 f = *(const float4*)src;
  u16x4 o; o[0]=f2bf(f.x); o[1]=f2bf(f.y); o[2]=f2bf(f.z); o[3]=f2bf(f.w);
  *(u16x4*)dst = o;
  if (g < 2048) biasuv[g] = (g < 1024) ? bu[g] : bv[g - 1024];
}

// ------------- T matrices: T[h] = (Wm U)(Wm V)^T, 64x64 per head ----------
__global__ void k_toep(const float* __restrict__ U1, const float* __restrict__ V1,
                       const float* __restrict__ U2, const float* __restrict__ V2,
                       u16* __restrict__ T1b, u16* __restrict__ T2b) {
  __shared__ float Us[512], Vs[512];
  int bid = blockIdx.x, t = threadIdx.x;
  int which = bid >> 6, rest = bid & 63, h = rest >> 3, seg = rest & 7;
  const float* U = which ? U2 : U1;
  const float* V = which ? V2 : V1;
  u16* T = which ? T2b : T1b;
  float scale = which ? 2.0f : 1.0f;
  for (int i = t; i < 512; i += 256) { Us[i] = U[h*512 + i]; Vs[i] = V[h*512 + i]; }
  __syncthreads();
  for (int q = 0; q < 2; ++q) {
    int e = seg * 512 + q * 256 + t;               // 0..4095 per head
    int i = e >> 6, j = e & 63;
    float pi = 1.0f / (float)(i + 1); float tvi = pi * 15.0f;
    int ii = min((int)floorf(tvi), 14); float fi = tvi - (float)ii;
    float pj = 1.0f / (float)(j + 1); float tvj = pj * 15.0f;
    int jj = min((int)floorf(tvj), 14); float fj = tvj - (float)jj;
    float s = 0.0f;
    #pragma unroll
    for (int r = 0; r < 32; ++r) {
      float a = (1.0f - fi) * Us[ii*32 + r] + fi * Us[(ii+1)*32 + r];
      float b = (1.0f - fj) * Vs[jj*32 + r] + fj * Vs[(jj+1)*32 + r];
      s += a * b;
    }
    T[h*4096 + i*64 + j] = f2bf(s * scale);
  }
}

// ============ persistent 256x256 bf16 B^T GEMM, phase-gated 8-phase ========
// C[m,n] = sum_k A[m,k]*B[n,k] (+bias[n]); EPI 0: silu->bf16, EPI 1: f32.
// Grid = 256 (1 block/CU). Block e: bn = e&(2^LGNBN-1) fixed, bm = (e>>LGNBN)
// + s*(256/NSEQ) for s = 0..NSEQ-1. K-tile index runs CONTINUOUSLY over
// s*NT+kt so the staging pipeline (2-tile lookahead, counted vmcnt) never
// drains at output-tile switches; per-seq epilogue runs with next-seq loads
// in flight. Staging/liveness schedule identical to r3 (race-free proof
// depends only on the continuous tile index).
template<int EPI, int K, int NSEQ, int LGNBN, int LDC>
__global__ __launch_bounds__(512, 2) void k_gemm256(
    const u16* __restrict__ A, const u16* __restrict__ B,
    const float* __restrict__ bias, void* __restrict__ C) {
  constexpr int NT = K >> 6;
  constexpr int LGNT = (NT == 8) ? 3 : 4;
  constexpr int TOT = NSEQ * NT;
  constexpr int SMSTEP = 256 / NSEQ;
  constexpr size_t SEQA = (size_t)SMSTEP * 256 * K;   // elems per seq A-step
  extern __shared__ uint4 smem4[];
  u16* lds = (u16*)smem4;
  const int t = threadIdx.x;
  const int l = t & 63, w = t >> 6;
  const int wmi = w >> 2, wni = w & 3;
  const int e = (blockIdx.x & 7) * 32 + (blockIdx.x >> 3);   // XCD swizzle
  const int bn = e & ((1 << LGNBN) - 1);
  const int bm0 = e >> LGNBN;
  const u16* Ab = A + (size_t)bm0 * 256 * K;
  const u16* Bb = B + (size_t)bn * 256 * K;

  f32x4 acc[8][4];                     // [h*4+f][nf]
  #pragma unroll
  for (int i = 0; i < 8; ++i)
    #pragma unroll
    for (int j = 0; j < 4; ++j) acc[i][j] = (f32x4){0.f, 0.f, 0.f, 0.f};

  float bcol[4];
  #pragma unroll
  for (int nf = 0; nf < 4; ++nf)
    bcol[nf] = bias[bn * 256 + (wni << 6) + nf * 16 + (l & 15)];

#define STAGE(TILE, HALF) do {                                               \
    int _t = (TILE);                                                         \
    int _seq = _t >> LGNT;                                                   \
    size_t _kt = (size_t)((_t & (NT - 1)) << 6);                             \
    const u16* _src = ((HALF) < 2) ? (Ab + (size_t)_seq * SEQA) : Bb;        \
    constexpr int _rowbase = ((HALF) & 1) << 7;                              \
    u16* _dst = lds + (_t & 1) * 32768 + (((HALF) >= 2) ? 16384 : 0)         \
                + _rowbase * 64;                                             \
    _Pragma("unroll")                                                        \
    for (int _j = 0; _j < 2; ++_j) {                                         \
      int _idx = _j * 512 + t;                                               \
      int _rr = _idx >> 3, _s8 = _idx & 7;                                   \
      int _R = _rowbase + _rr;                                               \
      int _col = (_s8 ^ (_R & 7)) << 3;                                      \
      gload_lds16(_src + (size_t)_R * K + _kt + _col, _dst + _idx * 8);      \
    }                                                                        \
  } while (0)

#define READ_A(hh, fp) do {                                                  \
    _Pragma("unroll")                                                        \
    for (int ks = 0; ks < 2; ++ks)                                           \
      _Pragma("unroll")                                                      \
      for (int i = 0; i < 2; ++i) {                                          \
        int R = ((hh) << 7) + (wmi << 6) + ((fp) * 2 + i) * 16 + (l & 15);   \
        int q8 = ks * 4 + (l >> 4);                                          \
        af[ks*2+i] = *(const bf16x8*)&As[R * 64 + ((q8 ^ (R & 7)) << 3)];    \
      }                                                                      \
  } while (0)

#define MFMA_PHASE(hh, fp) do {                                              \
    __builtin_amdgcn_s_setprio(1);                                           \
    _Pragma("unroll")                                                        \
    for (int ks = 0; ks < 2; ++ks)                                           \
      _Pragma("unroll")                                                      \
      for (int i = 0; i < 2; ++i)                                            \
        _Pragma("unroll")                                                    \
        for (int nf = 0; nf < 4; ++nf)                                       \
          acc[(hh)*4+(fp)*2+i][nf] = __builtin_amdgcn_mfma_f32_16x16x32_bf16(\
              af[ks*2+i], bfv[ks*4+nf], acc[(hh)*4+(fp)*2+i][nf], 0, 0, 0);  \
    __builtin_amdgcn_s_setprio(0);                                           \
  } while (0)

  // prologue: tile0 {A0,A1,B0,B1} then tile1 {B0,B1,A0}; drain tile0 only.
  STAGE(0, 0); STAGE(0, 1); STAGE(0, 2); STAGE(0, 3);
  STAGE(1, 2); STAGE(1, 3); STAGE(1, 0);
  asm volatile("s_waitcnt vmcnt(6)");
  __builtin_amdgcn_s_barrier();

  for (int tile = 0; tile < TOT; ++tile) {
    const u16* As = lds + (tile & 1) * 32768;
    const u16* Bs = As + 16384;
    bf16x8 bfv[8];                       // [ks*4+nf], held all 4 phases
    bf16x8 af[4];                        // [ks*2+i], per phase

    // ---------- phase 0: B(8 reads) + A h0 f0-1; issue (t+1).A1 ----------
    #pragma unroll
    for (int ks = 0; ks < 2; ++ks)
      #pragma unroll
      for (int nf = 0; nf < 4; ++nf) {
        int R = (wni << 6) + nf * 16 + (l & 15);
        int q8 = ks * 4 + (l >> 4);
        bfv[ks*4+nf] = *(const bf16x8*)&Bs[R * 64 + ((q8 ^ (R & 7)) << 3)];
      }
    READ_A(0, 0);
    if (tile + 1 < TOT) STAGE(tile + 1, 1);
    __builtin_amdgcn_s_barrier();
    asm volatile("s_waitcnt lgkmcnt(0)");
    MFMA_PHASE(0, 0);
    __builtin_amdgcn_s_barrier();

    // ---------- phase 1: A h0 f2-3; issue (t+2).B0,B1; vmcnt gate ----------
    READ_A(0, 1);
    if (tile + 2 < TOT) { STAGE(tile + 2, 2); STAGE(tile + 2, 3); }
    __builtin_amdgcn_s_barrier();
    asm volatile("s_waitcnt lgkmcnt(0)");
    MFMA_PHASE(0, 1);
    if (tile < TOT - 2)       asm volatile("s_waitcnt vmcnt(12)");
    else if (tile == TOT - 2) asm volatile("s_waitcnt vmcnt(8)");
    else                      asm volatile("s_waitcnt vmcnt(0)");
    __builtin_amdgcn_s_barrier();

    // ---------- phase 2: A h1 f0-1; issue (t+2).A0 ----------
    READ_A(1, 0);
    if (tile + 2 < TOT) STAGE(tile + 2, 0);
    __builtin_amdgcn_s_barrier();
    asm volatile("s_waitcnt lgkmcnt(0)");
    MFMA_PHASE(1, 0);
    __builtin_amdgcn_s_barrier();

    // ---------- phase 3: A h1 f2-3; vmcnt gate for next tile ----------
    READ_A(1, 1);
    __builtin_amdgcn_s_barrier();
    asm volatile("s_waitcnt lgkmcnt(0)");
    MFMA_PHASE(1, 1);
    if (tile < TOT - 2)       asm volatile("s_waitcnt vmcnt(8)");
    else if (tile == TOT - 2) asm volatile("s_waitcnt vmcnt(2)");
    __builtin_amdgcn_s_barrier();

    // ---------- per-seq epilogue (loads for next seq stay in flight) ------
    if ((tile & (NT - 1)) == NT - 1) {
      int s = tile >> LGNT;
      int bmbase = (bm0 + s * SMSTEP) * 256;
      #pragma unroll
      for (int hf = 0; hf < 8; ++hf) {
        int gm0 = bmbase + (hf >> 2) * 128 + wmi * 64 + (hf & 3) * 16 + (l >> 4) * 4;
        #pragma unroll
        for (int nf = 0; nf < 4; ++nf) {
          int gn = bn * 256 + (wni << 6) + nf * 16 + (l & 15);
          #pragma unroll
          for (int r = 0; r < 4; ++r) {
            float z = acc[hf][nf][r] + bcol[nf];
            size_t off = (size_t)(gm0 + r) * LDC + gn;
            if (EPI == 0) {
              z = z / (1.0f + __expf(-z));           // silu
              ((u16*)C)[off] = f2bf(z);
            } else {
              ((float*)C)[off] = z;
            }
          }
        }
      }
      #pragma unroll
      for (int i = 0; i < 8; ++i)
        #pragma unroll
        for (int j = 0; j < 4; ++j) acc[i][j] = (f32x4){0.f, 0.f, 0.f, 0.f};
    }
  }
#undef STAGE
#undef READ_A
#undef MFMA_PHASE
}

// ------------- mixing pass: per (b,outer,h): Out = T @ In (64x64 @ 64x128) -
template<int PASS>
__global__ __launch_bounds__(256) void k_mix(const u16* __restrict__ uv,
                                             u16* __restrict__ y,
                                             const u16* __restrict__ Tmat) {
  __shared__ alignas(16) u16 Ts[64 * 72];     // T padded rows (72 elems)
  __shared__ alignas(16) u32 VT[128 * 36];    // transposed input, swizzled
  int bid = blockIdx.x, t = threadIdx.x;
  int h = bid & 7, outer = (bid >> 3) & 63, b = bid >> 9;
  int l = t & 63, w = t >> 6;

  { // stage T[h] (64x64 bf16) into padded LDS
    const u16* Tg = Tmat + h * 4096;
    int rr = t >> 2, cc = (t & 3) * 16;
    const uint4* src = (const uint4*)(Tg + rr * 64 + cc);
    uint4 v0 = src[0], v1 = src[1];
    *(uint4*)&Ts[rr * 72 + cc] = v0;
    *(uint4*)&Ts[rr * 72 + cc + 8] = v1;
  }

  size_t inbase; size_t instride;
  if (PASS == 0) { inbase = ((size_t)(b*64 + outer) * 64) * 2048 + 1024 + h*128; instride = 2048; }
  else           { inbase = ((size_t)b * 4096 + outer) * 1024 + h*128;            instride = 65536; }
  const u16* inp = (PASS == 0) ? uv : (const u16*)y;

  #pragma unroll
  for (int a2 = 0; a2 < 2; ++a2) {
    int jp = (t >> 4) + a2 * 16;                 // row-pair 0..31 (rows 2jp,2jp+1)
    int dc = t & 15;                             // d-chunk of 8
    const u16* r0 = inp + inbase + (size_t)(2*jp) * instride + dc * 8;
    const u16* r1 = r0 + instride;
    uint4 av = *(const uint4*)r0;
    uint4 bv = *(const uint4*)r1;
    u32 a4[4] = {av.x, av.y, av.z, av.w};
    u32 b4[4] = {bv.x, bv.y, bv.z, bv.w};
    #pragma unroll
    for (int ww = 0; ww < 4; ++ww) {
      u32 lo = (a4[ww] & 0xffffu) | (b4[ww] << 16);        // d even
      u32 hi = (a4[ww] >> 16) | (b4[ww] & 0xffff0000u);    // d odd
      int d0 = dc * 8 + 2 * ww, d1 = d0 + 1;
      VT[d0 * 36 + (jp ^ ((((u32)d0 >> 3) & 7) << 2))] = lo;
      VT[d1 * 36 + (jp ^ ((((u32)d1 >> 3) & 7) << 2))] = hi;
    }
  }
  __syncthreads();

  f32x4 acc[8];
  #pragma unroll
  for (int nf = 0; nf < 8; ++nf) acc[nf] = (f32x4){0.f, 0.f, 0.f, 0.f};
  #pragma unroll
  for (int ks = 0; ks < 2; ++ks) {
    bf16x8 af = *(const bf16x8*)&Ts[(w*16 + (l & 15)) * 72 + ks*32 + (l >> 4)*8];
    #pragma unroll
    for (int nf = 0; nf < 8; ++nf) {
      int d  = nf * 16 + (l & 15);
      int kd = ks * 16 + (l >> 4) * 4;
      u32 dw = (u32)d * 36 + ((u32)kd ^ ((((u32)d >> 3) & 7) << 2));
      bf16x8 bfv = *(const bf16x8*)&VT[dw];
      acc[nf] = __builtin_amdgcn_mfma_f32_16x16x32_bf16(af, bfv, acc[nf], 0, 0, 0);
    }
  }

  size_t obase, ostride, ubase = 0;
  if (PASS == 0) { obase = ((size_t)(b*64 + outer) * 64) * 1024 + h*128; ostride = 1024; }
  else {
    obase = ((size_t)b * 4096 + outer) * 1024 + h*128; ostride = 65536;
    ubase = ((size_t)b * 4096 + outer) * 2048 + h*128;
  }
  #pragma unroll
  for (int nf = 0; nf < 8; ++nf) {
    int d = nf * 16 + (l & 15);
    #pragma unroll
    for (int r = 0; r < 4; ++r) {
      int m = w * 16 + (l >> 4) * 4 + r;
      float val = acc[nf][r];
      if (PASS == 1) val *= bf2f(uv[ubase + (size_t)m * 131072 + d]);
      y[obase + (size_t)m * ostride + d] = f2bf(val);
    }
  }
}

// ---------------------------------------------------------------------------
extern "C" void kernel_launch(void* const* d_in, const int* in_sizes, int n_in,
                              void* d_out, int out_size, void* d_ws, size_t ws_size,
                              hipStream_t stream) {
  const float* x  = (const float*)d_in[0];
  const float* Wu = (const float*)d_in[1];
  const float* bu = (const float*)d_in[2];
  const float* Wv = (const float*)d_in[3];
  const float* bv = (const float*)d_in[4];
  const float* Wo = (const float*)d_in[5];
  const float* bo = (const float*)d_in[6];
  const float* U1 = (const float*)d_in[7];
  const float* V1 = (const float*)d_in[8];
  const float* U2 = (const float*)d_in[9];
  const float* V2 = (const float*)d_in[10];
  float* out = (float*)d_out;

  char* p = (char*)d_ws;
  u16*  xb     = (u16*)(p + 0);              //  67,108,864 B
  u16*  wuvb   = (u16*)(p + 67108864);       //   2,097,152 B
  u16*  wob    = (u16*)(p + 69206016);       //   1,048,576 B
  u16*  T1b    = (u16*)(p + 70254592);       //      65,536 B
  u16*  T2b    = (u16*)(p + 70320128);       //      65,536 B
  float* biasuv= (float*)(p + 70385664);     //       8,192 B
  u16*  uv     = (u16*)(p + 70393856);       // 268,435,456 B  (u|v, ld 2048)
  u16*  y      = (u16*)(p + 338829312);      // 134,217,728 B  -> end 473,047,040
  if (ws_size < 473047040ULL) return;        // insufficient scratch: visible fail

  // allow 128 KiB dynamic LDS (ignore failures; ROCm typically allows directly)
  (void)hipFuncSetAttribute((const void*)&k_gemm256<0, 512, 8, 3, 2048>,
      hipFuncAttributeMaxDynamicSharedMemorySize, 131072);
  (void)hipFuncSetAttribute((const void*)&k_gemm256<1, 1024, 2, 1, 512>,
      hipFuncAttributeMaxDynamicSharedMemorySize, 131072);

  k_conv_x<<<16384, 256, 0, stream>>>(x, xb);
  k_conv_w<<<1536, 256, 0, stream>>>(Wu, Wv, Wo, bu, bv, wuvb, wob, biasuv);
  k_toep<<<128, 256, 0, stream>>>(U1, V1, U2, V2, T1b, T2b);
  // uv = [silu(x Wu^T + bu) | silu(x Wv^T + bv)]  (M=65536, N=2048, K=512)
  k_gemm256<0, 512, 8, 3, 2048><<<256, 512, 131072, stream>>>(xb, wuvb, biasuv, (void*)uv);
  // y = T1-mix along W of v
  k_mix<0><<<8192, 256, 0, stream>>>(uv, y, T1b);
  // y = u * (2*T2)-mix along H of y   (in-place, gated)
  k_mix<1><<<8192, 256, 0, stream>>>(uv, y, T2b);
  // out = y Wo^T + bo  (M=65536, N=512, K=1024)
  k_gemm256<1, 1024, 2, 1, 512><<<256, 512, 131072, stream>>>(y, wob, bo, (void*)out);
}

// Round 8
// 512.393 us; speedup vs baseline: 1.0132x; 1.0116x over previous
//
#include <hip/hip_runtime.h>
#include <hip/hip_bf16.h>

typedef unsigned short u16;
typedef unsigned int   u32;
typedef float  f32x4  __attribute__((ext_vector_type(4)));
typedef __bf16 bf16x8 __attribute__((ext_vector_type(8)));
typedef u16    u16x8  __attribute__((ext_vector_type(8)));
typedef u16    u16x4  __attribute__((ext_vector_type(4)));

__device__ __forceinline__ u16 f2bf(float f) {
  u32 x = __builtin_bit_cast(u32, f);
  x += 0x7fffu + ((x >> 16) & 1u);          // RNE
  return (u16)(x >> 16);
}
__device__ __forceinline__ float bf2f(u16 u) {
  return __builtin_bit_cast(float, (u32)u << 16);
}
__device__ __forceinline__ void gload_lds16(const u16* g, u16* l) {
  __builtin_amdgcn_global_load_lds(
      (const __attribute__((address_space(1))) void*)g,
      (__attribute__((address_space(3))) void*)l, 16, 0, 0);
}

// ---------------- convert x -> bf16 (each thread: 8 elems) ----------------
__global__ void k_conv_x(const float* __restrict__ x, u16* __restrict__ xb) {
  int g = blockIdx.x * 256 + threadIdx.x;          // 4,194,304 threads exact
  const float4* src = (const float4*)(x + (size_t)g * 8);
  float4 f0 = src[0], f1 = src[1];
  u16x8 o;
  o[0]=f2bf(f0.x); o[1]=f2bf(f0.y); o[2]=f2bf(f0.z); o[3]=f2bf(f0.w);
  o[4]=f2bf(f1.x); o[5]=f2bf(f1.y); o[6]=f2bf(f1.z); o[7]=f2bf(f1.w);
  *(u16x8*)(xb + (size_t)g * 8) = o;
}

// ------------- convert weights -> bf16, build concat bias -----------------
__global__ void k_conv_w(const float* __restrict__ Wu, const float* __restrict__ Wv,
                         const float* __restrict__ Wo, const float* __restrict__ bu,
                         const float* __restrict__ bv, u16* __restrict__ wuvb,
                         u16* __restrict__ wob, float* __restrict__ biasuv) {
  int g = blockIdx.x * 256 + threadIdx.x;          // 393,216 threads exact
  int e = g * 4;
  const float* src; u16* dst;
  if (e < 524288)        { src = Wu + e;             dst = wuvb + e; }
  else if (e < 1048576)  { src = Wv + (e - 524288);  dst = wuvb + e; }
  else                   { src = Wo + (e - 1048576); dst = wob + (e - 1048576); }
  float4 f = *(const float4*)src;
  u16x4 o; o[0]=f2bf(f.x); o[1]=f2bf(f.y); o[2]=f2bf(f.z); o[3]=f2bf(f.w);
  *(u16x4*)dst = o;
  if (g < 2048) biasuv[g] = (g < 1024) ? bu[g] : bv[g - 1024];
}

// ------------- T matrices: T[h] = (Wm U)(Wm V)^T, 64x64 per head ----------
__global__ void k_toep(const float* __restrict__ U1, const float* __restrict__ V1,
                       const float* __restrict__ U2, const float* __restrict__ V2,
                       u16* __restrict__ T1b, u16* __restrict__ T2b) {
  __shared__ float Us[512], Vs[512];
  int bid = blockIdx.x, t = threadIdx.x;
  int which = bid >> 6, rest = bid & 63, h = rest >> 3, seg = rest & 7;
  const float* U = which ? U2 : U1;
  const float* V = which ? V2 : V1;
  u16* T = which ? T2b : T1b;
  float scale = which ? 2.0f : 1.0f;
  for (int i = t; i < 512; i += 256) { Us[i] = U[h*512 + i]; Vs[i] = V[h*512 + i]; }
  __syncthreads();
  for (int q = 0; q < 2; ++q) {
    int e = seg * 512 + q * 256 + t;               // 0..4095 per head
    int i = e >> 6, j = e & 63;
    float pi = 1.0f / (float)(i + 1); float tvi = pi * 15.0f;
    int ii = min((int)floorf(tvi), 14); float fi = tvi - (float)ii;
    float pj = 1.0f / (float)(j + 1); float tvj = pj * 15.0f;
    int jj = min((int)floorf(tvj), 14); float fj = tvj - (float)jj;
    float s = 0.0f;
    #pragma unroll
    for (int r = 0; r < 32; ++r) {
      float a = (1.0f - fi) * Us[ii*32 + r] + fi * Us[(ii+1)*32 + r];
      float b = (1.0f - fj) * Vs[jj*32 + r] + fj * Vs[(jj+1)*32 + r];
      s += a * b;
    }
    T[h*4096 + i*64 + j] = f2bf(s * scale);
  }
}

// ============ persistent 256x256 bf16 B^T GEMM, 3-barrier schedule =========
// C[m,n] = sum_k A[m,k]*B[n,k] (+bias[n]); EPI 0: silu->bf16, EPI 1: f32.
// Grid = 256 (1 block/CU). K-tile index runs continuously over seqs.
// Minimal barrier set (hazard-derived):
//   BARRIER_A @P0-end : cur.B readers (P0) vs STAGE(t+2,B) writes @P1
//   BARRIER_B @P1-end : cur.A0 readers (P0,P1) vs STAGE(t+2,A0) @P2; +vmcnt gate
//   BARRIER_C @P3-end : cur.A1 readers (P2,P3) vs STAGE(t+2,A1) @P0 of t+1; +gate
// Mid-phase barriers + P2-end barrier removed: each wave's compiler-emitted
// lgkm waits seal its own reads before it reaches the kept barriers; stage
// writes never alias a live region between two kept barriers (see derivation
// in round-8 notes). vmcnt gate counts unchanged from r3 (12 @P1, 8 @P3;
// prologue 6; tail 8/2/0).
template<int EPI, int K, int NSEQ, int LGNBN, int LDC>
__global__ __launch_bounds__(512, 2) void k_gemm256(
    const u16* __restrict__ A, const u16* __restrict__ B,
    const float* __restrict__ bias, void* __restrict__ C) {
  constexpr int NT = K >> 6;
  constexpr int LGNT = (NT == 8) ? 3 : 4;
  constexpr int TOT = NSEQ * NT;
  constexpr int SMSTEP = 256 / NSEQ;
  constexpr size_t SEQA = (size_t)SMSTEP * 256 * K;   // elems per seq A-step
  extern __shared__ uint4 smem4[];
  u16* lds = (u16*)smem4;
  const int t = threadIdx.x;
  const int l = t & 63, w = t >> 6;
  const int wmi = w >> 2, wni = w & 3;
  const int e = (blockIdx.x & 7) * 32 + (blockIdx.x >> 3);   // XCD swizzle
  const int bn = e & ((1 << LGNBN) - 1);
  const int bm0 = e >> LGNBN;
  const u16* Ab = A + (size_t)bm0 * 256 * K;
  const u16* Bb = B + (size_t)bn * 256 * K;

  f32x4 acc[8][4];                     // [h*4+f][nf]
  #pragma unroll
  for (int i = 0; i < 8; ++i)
    #pragma unroll
    for (int j = 0; j < 4; ++j) acc[i][j] = (f32x4){0.f, 0.f, 0.f, 0.f};

  float bcol[4];
  #pragma unroll
  for (int nf = 0; nf < 4; ++nf)
    bcol[nf] = bias[bn * 256 + (wni << 6) + nf * 16 + (l & 15)];

#define STAGE(TILE, HALF) do {                                               \
    int _t = (TILE);                                                         \
    int _seq = _t >> LGNT;                                                   \
    size_t _kt = (size_t)((_t & (NT - 1)) << 6);                             \
    const u16* _src = ((HALF) < 2) ? (Ab + (size_t)_seq * SEQA) : Bb;        \
    constexpr int _rowbase = ((HALF) & 1) << 7;                              \
    u16* _dst = lds + (_t & 1) * 32768 + (((HALF) >= 2) ? 16384 : 0)         \
                + _rowbase * 64;                                             \
    _Pragma("unroll")                                                        \
    for (int _j = 0; _j < 2; ++_j) {                                         \
      int _idx = _j * 512 + t;                                               \
      int _rr = _idx >> 3, _s8 = _idx & 7;                                   \
      int _R = _rowbase + _rr;                                               \
      int _col = (_s8 ^ (_R & 7)) << 3;                                      \
      gload_lds16(_src + (size_t)_R * K + _kt + _col, _dst + _idx * 8);      \
    }                                                                        \
  } while (0)

#define READ_A(hh, fp) do {                                                  \
    _Pragma("unroll")                                                        \
    for (int ks = 0; ks < 2; ++ks)                                           \
      _Pragma("unroll")                                                      \
      for (int i = 0; i < 2; ++i) {                                          \
        int R = ((hh) << 7) + (wmi << 6) + ((fp) * 2 + i) * 16 + (l & 15);   \
        int q8 = ks * 4 + (l >> 4);                                          \
        af[ks*2+i] = *(const bf16x8*)&As[R * 64 + ((q8 ^ (R & 7)) << 3)];    \
      }                                                                      \
  } while (0)

#define MFMA_PHASE(hh, fp) do {                                              \
    __builtin_amdgcn_s_setprio(1);                                           \
    _Pragma("unroll")                                                        \
    for (int ks = 0; ks < 2; ++ks)                                           \
      _Pragma("unroll")                                                      \
      for (int i = 0; i < 2; ++i)                                            \
        _Pragma("unroll")                                                    \
        for (int nf = 0; nf < 4; ++nf)                                       \
          acc[(hh)*4+(fp)*2+i][nf] = __builtin_amdgcn_mfma_f32_16x16x32_bf16(\
              af[ks*2+i], bfv[ks*4+nf], acc[(hh)*4+(fp)*2+i][nf], 0, 0, 0);  \
    __builtin_amdgcn_s_setprio(0);                                           \
  } while (0)

  // prologue: tile0 {A0,A1,B0,B1} then tile1 {B0,B1,A0}; drain tile0 only.
  STAGE(0, 0); STAGE(0, 1); STAGE(0, 2); STAGE(0, 3);
  STAGE(1, 2); STAGE(1, 3); STAGE(1, 0);
  asm volatile("s_waitcnt vmcnt(6)");
  __builtin_amdgcn_s_barrier();

  for (int tile = 0; tile < TOT; ++tile) {
    const u16* As = lds + (tile & 1) * 32768;
    const u16* Bs = As + 16384;
    bf16x8 bfv[8];                       // [ks*4+nf], held all 4 phases
    bf16x8 af[4];                        // [ks*2+i], per phase

    // ---- P0: read B(8) + A h0 f0-1; issue (t+1).A1; MFMA; BARRIER_A ----
    #pragma unroll
    for (int ks = 0; ks < 2; ++ks)
      #pragma unroll
      for (int nf = 0; nf < 4; ++nf) {
        int R = (wni << 6) + nf * 16 + (l & 15);
        int q8 = ks * 4 + (l >> 4);
        bfv[ks*4+nf] = *(const bf16x8*)&Bs[R * 64 + ((q8 ^ (R & 7)) << 3)];
      }
    READ_A(0, 0);
    if (tile + 1 < TOT) STAGE(tile + 1, 1);
    MFMA_PHASE(0, 0);
    __builtin_amdgcn_s_barrier();                 // BARRIER_A

    // ---- P1: A h0 f2-3; issue (t+2).B0,B1; MFMA; gate; BARRIER_B ----
    READ_A(0, 1);
    if (tile + 2 < TOT) { STAGE(tile + 2, 2); STAGE(tile + 2, 3); }
    MFMA_PHASE(0, 1);
    if (tile < TOT - 2)       asm volatile("s_waitcnt vmcnt(12)");
    else if (tile == TOT - 2) asm volatile("s_waitcnt vmcnt(8)");
    else                      asm volatile("s_waitcnt vmcnt(0)");
    __builtin_amdgcn_s_barrier();                 // BARRIER_B

    // ---- P2: A h1 f0-1; issue (t+2).A0; MFMA; (no barrier) ----
    READ_A(1, 0);
    if (tile + 2 < TOT) STAGE(tile + 2, 0);
    MFMA_PHASE(1, 0);

    // ---- P3: A h1 f2-3; MFMA; gate; BARRIER_C ----
    READ_A(1, 1);
    MFMA_PHASE(1, 1);
    if (tile < TOT - 2)       asm volatile("s_waitcnt vmcnt(8)");
    else if (tile == TOT - 2) asm volatile("s_waitcnt vmcnt(2)");
    __builtin_amdgcn_s_barrier();                 // BARRIER_C

    // ---- per-seq epilogue (loads for next seq stay in flight) ----
    if ((tile & (NT - 1)) == NT - 1) {
      int s = tile >> LGNT;
      int bmbase = (bm0 + s * SMSTEP) * 256;
      #pragma unroll
      for (int hf = 0; hf < 8; ++hf) {
        int gm0 = bmbase + (hf >> 2) * 128 + wmi * 64 + (hf & 3) * 16 + (l >> 4) * 4;
        #pragma unroll
        for (int nf = 0; nf < 4; ++nf) {
          int gn = bn * 256 + (wni << 6) + nf * 16 + (l & 15);
          #pragma unroll
          for (int r = 0; r < 4; ++r) {
            float z = acc[hf][nf][r] + bcol[nf];
            size_t off = (size_t)(gm0 + r) * LDC + gn;
            if (EPI == 0) {
              z = z / (1.0f + __expf(-z));           // silu
              ((u16*)C)[off] = f2bf(z);
            } else {
              ((float*)C)[off] = z;
            }
          }
        }
      }
      #pragma unroll
      for (int i = 0; i < 8; ++i)
        #pragma unroll
        for (int j = 0; j < 4; ++j) acc[i][j] = (f32x4){0.f, 0.f, 0.f, 0.f};
    }
  }
#undef STAGE
#undef READ_A
#undef MFMA_PHASE
}

// ------------- mixing pass: per (b,outer,h): Out = T @ In (64x64 @ 64x128) -
template<int PASS>
__global__ __launch_bounds__(256) void k_mix(const u16* __restrict__ uv,
                                             u16* __restrict__ y,
                                             const u16* __restrict__ Tmat) {
  __shared__ alignas(16) u16 Ts[64 * 72];     // T padded rows (72 elems)
  __shared__ alignas(16) u32 VT[128 * 36];    // transposed input, swizzled
  int bid = blockIdx.x, t = threadIdx.x;
  int h = bid & 7, outer = (bid >> 3) & 63, b = bid >> 9;
  int l = t & 63, w = t >> 6;

  { // stage T[h] (64x64 bf16) into padded LDS
    const u16* Tg = Tmat + h * 4096;
    int rr = t >> 2, cc = (t & 3) * 16;
    const uint4* src = (const uint4*)(Tg + rr * 64 + cc);
    uint4 v0 = src[0], v1 = src[1];
    *(uint4*)&Ts[rr * 72 + cc] = v0;
    *(uint4*)&Ts[rr * 72 + cc + 8] = v1;
  }

  size_t inbase; size_t instride;
  if (PASS == 0) { inbase = ((size_t)(b*64 + outer) * 64) * 2048 + 1024 + h*128; instride = 2048; }
  else           { inbase = ((size_t)b * 4096 + outer) * 1024 + h*128;            instride = 65536; }
  const u16* inp = (PASS == 0) ? uv : (const u16*)y;

  #pragma unroll
  for (int a2 = 0; a2 < 2; ++a2) {
    int jp = (t >> 4) + a2 * 16;                 // row-pair 0..31 (rows 2jp,2jp+1)
    int dc = t & 15;                             // d-chunk of 8
    const u16* r0 = inp + inbase + (size_t)(2*jp) * instride + dc * 8;
    const u16* r1 = r0 + instride;
    uint4 av = *(const uint4*)r0;
    uint4 bv = *(const uint4*)r1;
    u32 a4[4] = {av.x, av.y, av.z, av.w};
    u32 b4[4] = {bv.x, bv.y, bv.z, bv.w};
    #pragma unroll
    for (int ww = 0; ww < 4; ++ww) {
      u32 lo = (a4[ww] & 0xffffu) | (b4[ww] << 16);        // d even
      u32 hi = (a4[ww] >> 16) | (b4[ww] & 0xffff0000u);    // d odd
      int d0 = dc * 8 + 2 * ww, d1 = d0 + 1;
      VT[d0 * 36 + (jp ^ ((((u32)d0 >> 3) & 7) << 2))] = lo;
      VT[d1 * 36 + (jp ^ ((((u32)d1 >> 3) & 7) << 2))] = hi;
    }
  }
  __syncthreads();

  f32x4 acc[8];
  #pragma unroll
  for (int nf = 0; nf < 8; ++nf) acc[nf] = (f32x4){0.f, 0.f, 0.f, 0.f};
  #pragma unroll
  for (int ks = 0; ks < 2; ++ks) {
    bf16x8 af = *(const bf16x8*)&Ts[(w*16 + (l & 15)) * 72 + ks*32 + (l >> 4)*8];
    #pragma unroll
    for (int nf = 0; nf < 8; ++nf) {
      int d  = nf * 16 + (l & 15);
      int kd = ks * 16 + (l >> 4) * 4;
      u32 dw = (u32)d * 36 + ((u32)kd ^ ((((u32)d >> 3) & 7) << 2));
      bf16x8 bfv = *(const bf16x8*)&VT[dw];
      acc[nf] = __builtin_amdgcn_mfma_f32_16x16x32_bf16(af, bfv, acc[nf], 0, 0, 0);
    }
  }

  size_t obase, ostride, ubase = 0;
  if (PASS == 0) { obase = ((size_t)(b*64 + outer) * 64) * 1024 + h*128; ostride = 1024; }
  else {
    obase = ((size_t)b * 4096 + outer) * 1024 + h*128; ostride = 65536;
    ubase = ((size_t)b * 4096 + outer) * 2048 + h*128;
  }
  #pragma unroll
  for (int nf = 0; nf < 8; ++nf) {
    int d = nf * 16 + (l & 15);
    #pragma unroll
    for (int r = 0; r < 4; ++r) {
      int m = w * 16 + (l >> 4) * 4 + r;
      float val = acc[nf][r];
      if (PASS == 1) val *= bf2f(uv[ubase + (size_t)m * 131072 + d]);
      y[obase + (size_t)m * ostride + d] = f2bf(val);
    }
  }
}

// ---------------------------------------------------------------------------
extern "C" void kernel_launch(void* const* d_in, const int* in_sizes, int n_in,
                              void* d_out, int out_size, void* d_ws, size_t ws_size,
                              hipStream_t stream) {
  const float* x  = (const float*)d_in[0];
  const float* Wu = (const float*)d_in[1];
  const float* bu = (const float*)d_in[2];
  const float* Wv = (const float*)d_in[3];
  const float* bv = (const float*)d_in[4];
  const float* Wo = (const float*)d_in[5];
  const float* bo = (const float*)d_in[6];
  const float* U1 = (const float*)d_in[7];
  const float* V1 = (const float*)d_in[8];
  const float* U2 = (const float*)d_in[9];
  const float* V2 = (const float*)d_in[10];
  float* out = (float*)d_out;

  char* p = (char*)d_ws;
  u16*  xb     = (u16*)(p + 0);              //  67,108,864 B
  u16*  wuvb   = (u16*)(p + 67108864);       //   2,097,152 B
  u16*  wob    = (u16*)(p + 69206016);       //   1,048,576 B
  u16*  T1b    = (u16*)(p + 70254592);       //      65,536 B
  u16*  T2b    = (u16*)(p + 70320128);       //      65,536 B
  float* biasuv= (float*)(p + 70385664);     //       8,192 B
  u16*  uv     = (u16*)(p + 70393856);       // 268,435,456 B  (u|v, ld 2048)
  u16*  y      = (u16*)(p + 338829312);      // 134,217,728 B  -> end 473,047,040
  if (ws_size < 473047040ULL) return;        // insufficient scratch: visible fail

  // allow 128 KiB dynamic LDS (ignore failures; ROCm typically allows directly)
  (void)hipFuncSetAttribute((const void*)&k_gemm256<0, 512, 8, 3, 2048>,
      hipFuncAttributeMaxDynamicSharedMemorySize, 131072);
  (void)hipFuncSetAttribute((const void*)&k_gemm256<1, 1024, 2, 1, 512>,
      hipFuncAttributeMaxDynamicSharedMemorySize, 131072);

  k_conv_x<<<16384, 256, 0, stream>>>(x, xb);
  k_conv_w<<<1536, 256, 0, stream>>>(Wu, Wv, Wo, bu, bv, wuvb, wob, biasuv);
  k_toep<<<128, 256, 0, stream>>>(U1, V1, U2, V2, T1b, T2b);
  // uv = [silu(x Wu^T + bu) | silu(x Wv^T + bv)]  (M=65536, N=2048, K=512)
  k_gemm256<0, 512, 8, 3, 2048><<<256, 512, 131072, stream>>>(xb, wuvb, biasuv, (void*)uv);
  // y = T1-mix along W of v
  k_mix<0><<<8192, 256, 0, stream>>>(uv, y, T1b);
  // y = u * (2*T2)-mix along H of y   (in-place, gated)
  k_mix<1><<<8192, 256, 0, stream>>>(uv, y, T2b);
  // out = y Wo^T + bo  (M=65536, N=512, K=1024)
  k_gemm256<1, 1024, 2, 1, 512><<<256, 512, 131072, stream>>>(y, wob, bo, (void*)out);
}